// Round 4
// baseline (388.354 us; speedup 1.0000x reference)
//
#include <hip/hip_runtime.h>
#include <hip/hip_bf16.h>

static constexpr int Bn = 8, Cc = 288, Hh = 48, Ww = 48;
static constexpr int HW = Hh * Ww;          // 2304
static constexpr int Mtot = Bn * HW;        // 18432
static constexpr int NH = 9, HD = 32;
static constexpr int Cff = 2592;

typedef __attribute__((ext_vector_type(8))) short bf16x8;
typedef __attribute__((ext_vector_type(4))) float f32x4;

typedef const __attribute__((address_space(1))) unsigned gmem_word;
typedef __attribute__((address_space(3))) unsigned lds_word;

__device__ __forceinline__ void gload16(const void* g, void* l) {
    // async global->LDS, 16B per lane; LDS dest = wave-uniform base + lane*16
    __builtin_amdgcn_global_load_lds((gmem_word*)g, (lds_word*)l, 16, 0, 0);
}

// XOR swizzle: involution on byte addresses (bits 4-6 ^= bits 7-9)
__device__ __forceinline__ int swz(int byte) {
    return byte ^ (((byte >> 7) & 7) << 4);
}

// ---------------------------------------------------------------- transpose in
__global__ __launch_bounds__(256) void transpose_in(const float* __restrict__ x,
                                                    float* __restrict__ xl,
                                                    __hip_bfloat16* __restrict__ xlb) {
    __shared__ float tile[32][33];
    int b = blockIdx.z;
    int c0 = blockIdx.y * 32;
    int p0 = blockIdx.x * 32;
    int tx = threadIdx.x, ty = threadIdx.y;   // block (32,8)
#pragma unroll
    for (int q = 0; q < 4; ++q) {
        int c = c0 + ty + q * 8;
        tile[ty + q * 8][tx] = x[((size_t)b * Cc + c) * HW + p0 + tx];
    }
    __syncthreads();
#pragma unroll
    for (int q = 0; q < 4; ++q) {
        int p = p0 + ty + q * 8;
        float v = tile[tx][ty + q * 8];
        size_t idx = ((size_t)b * HW + p) * Cc + c0 + tx;
        xl[idx] = v;
        xlb[idx] = __float2bfloat16(v);
    }
}

// ---------------------------------------------------------------- weight repacks
__global__ __launch_bounds__(256) void repack_qkvt(const float* __restrict__ WQ,
                                                   const float* __restrict__ WK,
                                                   const float* __restrict__ WV,
                                                   __hip_bfloat16* __restrict__ Wt) {
    int t = blockIdx.x * 256 + threadIdx.x;
    if (t >= 3 * Cc * Cc) return;
    int n = t / Cc;
    int c = t % Cc;
    int g = n / Cc;
    int r = n % Cc;
    int h = r / HD, d = r % HD;
    const float* W = (g == 0) ? WQ : ((g == 1) ? WK : WV);
    Wt[t] = __float2bfloat16(W[((size_t)h * Cc + c) * HD + d]);
}

__global__ __launch_bounds__(256) void repack_wot(const float* __restrict__ WO,
                                                  __hip_bfloat16* __restrict__ Wt) {
    int t = blockIdx.x * 256 + threadIdx.x;
    if (t >= Cc * Cc) return;
    int n = t / Cc;
    int c = t % Cc;
    Wt[t] = __float2bfloat16(WO[(size_t)c * Cc + n]);
}

__global__ __launch_bounds__(256) void cast_bf16(const float* __restrict__ in,
                                                 __hip_bfloat16* __restrict__ out, int n) {
    int t = blockIdx.x * 256 + threadIdx.x;
    if (t < n) out[t] = __float2bfloat16(in[t]);
}

// ---------------------------------------------------------------- bf16 MFMA GEMM
// C (MxN) = A (MxK bf16 rm) * Bw^T, Bw (NxK bf16 rm) [+bias][relu]
// Tile 128x96, BK=32, 4 waves (2x2), wave tile 64x48. Swizzled LDS.
template <bool OUT_BF16, bool BIAS, bool RELU>
__global__ __launch_bounds__(256) void gemm_mfma(const __hip_bfloat16* __restrict__ A,
                                                 const __hip_bfloat16* __restrict__ Bw,
                                                 const float* __restrict__ bias,
                                                 void* __restrict__ Cout,
                                                 int M, int N, int K) {
    __shared__ __hip_bfloat16 As[2][128 * 32];
    __shared__ __hip_bfloat16 Bs[2][96 * 32];
    const int tid = threadIdx.x;
    const int wave = tid >> 6, lane = tid & 63;
    const int l16 = lane & 15, lq = lane >> 4;
    const int wr = wave >> 1, wc = wave & 1;
    const int bm = blockIdx.y * 128;
    const int bn = blockIdx.x * 96;
    const int nt = K >> 5;
    const char* Ab = (const char*)A;
    const char* Bb = (const char*)Bw;

    f32x4 acc[4][3] = {};

    auto stage = [&](int buf, int t) {
        const size_t k0b = (size_t)(t << 5) * 2;
        for (int c = wave; c < 14; c += 4) {
            if (c < 8) {
                int s = (c << 10) + lane * 16;
                int u = swz(s);
                int row = u >> 6, koff = u & 63;
                gload16(Ab + ((size_t)(bm + row) * K) * 2 + k0b + koff, &As[buf][c << 9]);
            } else {
                int s = ((c - 8) << 10) + lane * 16;
                int u = swz(s);
                int row = u >> 6, koff = u & 63;
                gload16(Bb + ((size_t)(bn + row) * K) * 2 + k0b + koff, &Bs[buf][(c - 8) << 9]);
            }
        }
    };

    int aoff[4], boff[3];
#pragma unroll
    for (int m = 0; m < 4; ++m)
        aoff[m] = swz((wr * 64 + m * 16 + l16) * 64 + lq * 16);
#pragma unroll
    for (int n = 0; n < 3; ++n)
        boff[n] = swz((wc * 48 + n * 16 + l16) * 64 + lq * 16);

    stage(0, 0);
    __syncthreads();
    int cur = 0;
    for (int t = 0; t < nt; ++t) {
        if (t + 1 < nt) stage(cur ^ 1, t + 1);
        const char* Ac = (const char*)&As[cur][0];
        const char* Bc = (const char*)&Bs[cur][0];
        bf16x8 a[4], b[3];
#pragma unroll
        for (int m = 0; m < 4; ++m) a[m] = *(const bf16x8*)(Ac + aoff[m]);
#pragma unroll
        for (int n = 0; n < 3; ++n) b[n] = *(const bf16x8*)(Bc + boff[n]);
#pragma unroll
        for (int m = 0; m < 4; ++m)
#pragma unroll
            for (int n = 0; n < 3; ++n)
                acc[m][n] = __builtin_amdgcn_mfma_f32_16x16x32_bf16(a[m], b[n], acc[m][n], 0, 0, 0);
        __syncthreads();
        cur ^= 1;
    }

#pragma unroll
    for (int m = 0; m < 4; ++m) {
#pragma unroll
        for (int n = 0; n < 3; ++n) {
            const int col = bn + wc * 48 + n * 16 + l16;
            const float bv = BIAS ? bias[col] : 0.f;
#pragma unroll
            for (int r = 0; r < 4; ++r) {
                const int row = bm + wr * 64 + m * 16 + lq * 4 + r;
                float v = acc[m][n][r] + bv;
                if (RELU) v = fmaxf(v, 0.f);
                if (OUT_BF16)
                    ((__hip_bfloat16*)Cout)[(size_t)row * N + col] = __float2bfloat16(v);
                else
                    ((float*)Cout)[(size_t)row * N + col] = v;
            }
        }
    }
}

// ---------------------------------------------------------------- fused FFN
// f2o = relu(yln*W1^T + b1)*W2^T + b2.  yln (M x 288 bf16), W1 (2592 x 288 bf16),
// W2 (288 x 2592 bf16), out f32 (M x 288).
// Block: 96 rows, 384 threads (6 waves: wr in {0,1} x wn in {0,1,2}).
// Per kc (27 chunks of 96 mid-channels): phase A computes T = relu(y*W1c^T+b1c)
// (96x96 bf16, LDS, swizzled); phase B: acc(96x288) += T * W2c^T.
// Operand fragments are read direct-to-register from global (L1/L2-hot slices).
__global__ __launch_bounds__(384) void fused_ffn(const __hip_bfloat16* __restrict__ Y,
                                                 const __hip_bfloat16* __restrict__ W1,
                                                 const __hip_bfloat16* __restrict__ W2,
                                                 const float* __restrict__ b1,
                                                 const float* __restrict__ b2,
                                                 float* __restrict__ out) {
    __shared__ __hip_bfloat16 T[96 * 96];   // 18 KB, swizzled storage
    const int tid = threadIdx.x;
    const int wave = tid >> 6, lane = tid & 63;
    const int l16 = lane & 15, lq = lane >> 4;
    const int wr = wave / 3;       // 0..1  (48-row half)
    const int wn = wave % 3;       // 0..2  (col third)
    const int R0 = blockIdx.x * 96;

    // Y fragment base pointers (row stride 576 B), advance by kk*64 within phase A
    const char* Yp[3];
#pragma unroll
    for (int m = 0; m < 3; ++m)
        Yp[m] = (const char*)Y + (size_t)(R0 + wr * 48 + m * 16 + l16) * 576 + lq * 16;
    // W2 fragment bases (row stride 5184 B), advance by kc*192 + kb*64
    const char* W2p[6];
#pragma unroll
    for (int n = 0; n < 6; ++n)
        W2p[n] = (const char*)W2 + (size_t)(wn * 96 + n * 16 + l16) * 5184 + lq * 16;
    // T read offsets (phase B a-frags)
    int toff[3];
#pragma unroll
    for (int m = 0; m < 3; ++m)
        toff[m] = (wr * 48 + m * 16 + l16) * 192 + lq * 16;

    f32x4 accB[3][6] = {};

    for (int kc = 0; kc < 27; ++kc) {
        // ---- phase A: T = relu(y * W1c^T + b1c), 96x96
        f32x4 accA[3][2] = {};
        const char* W1p[2];
#pragma unroll
        for (int n = 0; n < 2; ++n)
            W1p[n] = (const char*)W1 + (size_t)(kc * 96 + wn * 32 + n * 16 + l16) * 576 + lq * 16;
#pragma unroll
        for (int kk = 0; kk < 9; ++kk) {
            bf16x8 a[3], b[2];
#pragma unroll
            for (int m = 0; m < 3; ++m) a[m] = *(const bf16x8*)(Yp[m] + kk * 64);
#pragma unroll
            for (int n = 0; n < 2; ++n) b[n] = *(const bf16x8*)(W1p[n] + kk * 64);
#pragma unroll
            for (int m = 0; m < 3; ++m)
#pragma unroll
                for (int n = 0; n < 2; ++n)
                    accA[m][n] = __builtin_amdgcn_mfma_f32_16x16x32_bf16(a[m], b[n], accA[m][n], 0, 0, 0);
        }
        // pack T (bias + relu), C-layout -> [row][col] bf16 swizzled
#pragma unroll
        for (int m = 0; m < 3; ++m) {
#pragma unroll
            for (int n = 0; n < 2; ++n) {
                const int col = wn * 32 + n * 16 + l16;
                const float bb = b1[kc * 96 + col];
#pragma unroll
                for (int r = 0; r < 4; ++r) {
                    const int row = wr * 48 + m * 16 + lq * 4 + r;
                    float v = fmaxf(accA[m][n][r] + bb, 0.f);
                    *(__hip_bfloat16*)((char*)T + swz(row * 192 + col * 2)) = __float2bfloat16(v);
                }
            }
        }
        __syncthreads();   // T visible to all waves
        // ---- phase B: accB += T * W2c^T  (K = 96)
#pragma unroll
        for (int kb = 0; kb < 3; ++kb) {
            bf16x8 t[3], w[6];
#pragma unroll
            for (int m = 0; m < 3; ++m)
                t[m] = *(const bf16x8*)((const char*)T + swz(toff[m] + kb * 64));
#pragma unroll
            for (int n = 0; n < 6; ++n)
                w[n] = *(const bf16x8*)(W2p[n] + kc * 192 + kb * 64);
#pragma unroll
            for (int m = 0; m < 3; ++m)
#pragma unroll
                for (int n = 0; n < 6; ++n)
                    accB[m][n] = __builtin_amdgcn_mfma_f32_16x16x32_bf16(t[m], w[n], accB[m][n], 0, 0, 0);
        }
        __syncthreads();   // all T reads done before next kc overwrites
    }

    // epilogue: + b2, f32 out
#pragma unroll
    for (int m = 0; m < 3; ++m) {
#pragma unroll
        for (int n = 0; n < 6; ++n) {
            const int col = wn * 96 + n * 16 + l16;
            const float bb = b2[col];
#pragma unroll
            for (int r = 0; r < 4; ++r) {
                const int row = R0 + wr * 48 + m * 16 + lq * 4 + r;
                out[(size_t)row * Cc + col] = accB[m][n][r] + bb;
            }
        }
    }
}

// ---------------------------------------------------------------- attention
__global__ __launch_bounds__(256) void attn_kernel(const __hip_bfloat16* __restrict__ qkv,
                                                   __hip_bfloat16* __restrict__ aout) {
    int t = blockIdx.x * 256 + threadIdx.x;
    int d = t & 31;
    int ph = t >> 5;
    if (ph >= 16928 * 9) return;
    int h = ph % 9;
    int pix = ph / 9;
    int b = pix / (46 * 46);
    int r = pix % (46 * 46);
    int i = r / 46 + 1;
    int j = r % 46 + 1;
    int m = b * HW + i * Ww + j;
    int hd = h * HD + d;
    float q = __bfloat162float(qkv[(size_t)m * 864 + hd]);
    float logits[9];
    int mns[9];
#pragma unroll
    for (int n = 0; n < 9; ++n) {
        int di = n / 3, dj = n % 3;
        int mn = b * HW + (i - 1 + di) * Ww + (j - 1 + dj);
        mns[n] = mn;
        float kv = __bfloat162float(qkv[(size_t)mn * 864 + 288 + hd]);
        float p = q * kv;
#pragma unroll
        for (int s = 16; s >= 1; s >>= 1) p += __shfl_xor(p, s);
        logits[n] = p * 0.17677669529663687f;
    }
    float mx = logits[0];
#pragma unroll
    for (int n = 1; n < 9; ++n) mx = fmaxf(mx, logits[n]);
    float w[9];
    float sum = 0.f;
#pragma unroll
    for (int n = 0; n < 9; ++n) { w[n] = expf(logits[n] - mx); sum += w[n]; }
    float inv = 1.f / sum;
    float o = 0.f;
#pragma unroll
    for (int n = 0; n < 9; ++n)
        o += w[n] * __bfloat162float(qkv[(size_t)mns[n] * 864 + 576 + hd]);
    aout[(size_t)m * Cc + hd] = __float2bfloat16(o * inv);
}

// ---------------------------------------------------------------- LN1 + ReLU
__global__ __launch_bounds__(256) void ln_relu(const float* __restrict__ in,
                                               const float* __restrict__ g,
                                               const float* __restrict__ bta,
                                               __hip_bfloat16* __restrict__ out) {
    int wid = (blockIdx.x * 256 + threadIdx.x) >> 6;
    int lane = threadIdx.x & 63;
    if (wid >= Mtot) return;
    const float* row = in + (size_t)wid * Cc;
    float v[5];
    float sum = 0.f, sq = 0.f;
#pragma unroll
    for (int q = 0; q < 5; ++q) {
        int c = lane + q * 64;
        float x_ = (c < Cc) ? row[c] : 0.f;
        v[q] = x_; sum += x_; sq += x_ * x_;
    }
#pragma unroll
    for (int s = 32; s >= 1; s >>= 1) { sum += __shfl_xor(sum, s); sq += __shfl_xor(sq, s); }
    float mean = sum * (1.f / Cc);
    float var = sq * (1.f / Cc) - mean * mean;
    float rstd = rsqrtf(var + 1e-5f);
#pragma unroll
    for (int q = 0; q < 5; ++q) {
        int c = lane + q * 64;
        if (c < Cc) {
            float y = (v[q] - mean) * rstd * g[c] + bta[c];
            out[(size_t)wid * Cc + c] = __float2bfloat16(fmaxf(y, 0.f));
        }
    }
}

// ---------------------------------------------------------------- final
__global__ __launch_bounds__(256) void final_kernel(const float* __restrict__ in,
                                                    const float* __restrict__ xl,
                                                    const float* __restrict__ g,
                                                    const float* __restrict__ bta,
                                                    float* __restrict__ out) {
    int wid = (blockIdx.x * 256 + threadIdx.x) >> 6;
    int lane = threadIdx.x & 63;
    if (wid >= Mtot) return;
    int b = wid / HW;
    int p = wid % HW;
    const float* row = in + (size_t)wid * Cc;
    float v[5];
    float sum = 0.f, sq = 0.f;
#pragma unroll
    for (int q = 0; q < 5; ++q) {
        int c = lane + q * 64;
        float x_ = (c < Cc) ? row[c] : 0.f;
        v[q] = x_; sum += x_; sq += x_ * x_;
    }
#pragma unroll
    for (int s = 32; s >= 1; s >>= 1) { sum += __shfl_xor(sum, s); sq += __shfl_xor(sq, s); }
    float mean = sum * (1.f / Cc);
    float var = sq * (1.f / Cc) - mean * mean;
    float rstd = rsqrtf(var + 1e-5f);
#pragma unroll
    for (int q = 0; q < 5; ++q) {
        int c = lane + q * 64;
        if (c < Cc) {
            float y = (v[q] - mean) * rstd * g[c] + bta[c];
            float res = xl[(size_t)wid * Cc + c];
            out[((size_t)b * Cc + c) * HW + p] = fmaxf(y + res, 0.f);
        }
    }
}

__global__ void sentinel_kernel(float* out, float val) {
    out[threadIdx.x] = val;
}

extern "C" void kernel_launch(void* const* d_in, const int* in_sizes, int n_in,
                              void* d_out, int out_size, void* d_ws, size_t ws_size,
                              hipStream_t stream) {
    const float* x   = (const float*)d_in[0];
    const float* WQ  = (const float*)d_in[1];
    const float* WK  = (const float*)d_in[2];
    const float* WV  = (const float*)d_in[3];
    const float* WO  = (const float*)d_in[4];
    const float* f1w = (const float*)d_in[5];
    const float* f1b = (const float*)d_in[6];
    const float* f2w = (const float*)d_in[7];
    const float* f2b = (const float*)d_in[8];
    const float* g1  = (const float*)d_in[9];
    const float* b1  = (const float*)d_in[10];
    const float* g2  = (const float*)d_in[11];
    const float* b2  = (const float*)d_in[12];

    char* ws = (char*)d_ws;
    size_t off = 0;
    auto alloc = [&](size_t bytes) { void* p = ws + off; off += (bytes + 255) & ~(size_t)255; return p; };

    float*          xl    = (float*)alloc((size_t)Mtot * Cc * 4);
    __hip_bfloat16* xlb   = (__hip_bfloat16*)alloc((size_t)Mtot * Cc * 2);   // aliased by aout later
    __hip_bfloat16* wqkvt = (__hip_bfloat16*)alloc((size_t)3 * Cc * Cc * 2);
    char*           big   = (char*)alloc((size_t)Mtot * 3 * Cc * 2);          // qkv bf16 / ywo f32 / f2o f32
    __hip_bfloat16* wot   = (__hip_bfloat16*)alloc((size_t)Cc * Cc * 2);
    __hip_bfloat16* yln   = (__hip_bfloat16*)alloc((size_t)Mtot * Cc * 2);
    __hip_bfloat16* w1b   = (__hip_bfloat16*)alloc((size_t)Cff * Cc * 2);
    __hip_bfloat16* w2b   = (__hip_bfloat16*)alloc((size_t)Cff * Cc * 2);

    __hip_bfloat16* qkv  = (__hip_bfloat16*)big;   // live: QKV gemm -> attn
    __hip_bfloat16* aout = xlb;                    // live after xlb dead (post QKV gemm)
    float*          ywo  = (float*)big;            // live after qkv dead (post attn)
    float*          f2o  = (float*)big;            // live after ywo dead (post LN1)

    if (ws_size < off) {
        sentinel_kernel<<<1, 256, 0, stream>>>((float*)d_out, (float)off * 1e-6f);
        return;
    }

    transpose_in<<<dim3(HW / 32, Cc / 32, Bn), dim3(32, 8), 0, stream>>>(x, xl, xlb);
    repack_qkvt<<<(3 * Cc * Cc + 255) / 256, 256, 0, stream>>>(WQ, WK, WV, wqkvt);
    repack_wot<<<(Cc * Cc + 255) / 256, 256, 0, stream>>>(WO, wot);
    cast_bf16<<<(Cff * Cc + 255) / 256, 256, 0, stream>>>(f1w, w1b, Cff * Cc);
    cast_bf16<<<(Cff * Cc + 255) / 256, 256, 0, stream>>>(f2w, w2b, Cff * Cc);

    // QKV: (M x 288) * (288 x 864) -> bf16
    gemm_mfma<true, false, false><<<dim3(864 / 96, Mtot / 128), 256, 0, stream>>>(
        xlb, wqkvt, nullptr, qkv, Mtot, 3 * Cc, Cc);

    // attention (border rows of aout = 0 implements the zero-pad)
    hipMemsetAsync(aout, 0, (size_t)Mtot * Cc * 2, stream);
    attn_kernel<<<(16928 * 9 * 32) / 256, 256, 0, stream>>>(qkv, aout);

    // W_O: (M x 288) * (288 x 288) -> f32
    gemm_mfma<false, false, false><<<dim3(Cc / 96, Mtot / 128), 256, 0, stream>>>(
        aout, wot, nullptr, ywo, Mtot, Cc, Cc);

    // LN1 + ReLU -> bf16
    ln_relu<<<Mtot / 4, 256, 0, stream>>>(ywo, g1, b1, yln);

    // fused FFN1+FFN2 (mid never hits HBM)
    fused_ffn<<<Mtot / 96, 384, 0, stream>>>(yln, w1b, w2b, f1b, f2b, f2o);

    // LN2 + residual + ReLU + transpose to (B, C, H, W)
    final_kernel<<<Mtot / 4, 256, 0, stream>>>(f2o, xl, g2, b2, (float*)d_out);
}

// Round 5
// 270.549 us; speedup vs baseline: 1.4354x; 1.4354x over previous
//
#include <hip/hip_runtime.h>
#include <hip/hip_bf16.h>

static constexpr int Bn = 8, Cc = 288, Hh = 48, Ww = 48;
static constexpr int HW = Hh * Ww;          // 2304
static constexpr int Mtot = Bn * HW;        // 18432
static constexpr int NH = 9, HD = 32;
static constexpr int Cff = 2592;

typedef __attribute__((ext_vector_type(8))) short bf16x8;
typedef __attribute__((ext_vector_type(4))) float f32x4;

typedef const __attribute__((address_space(1))) unsigned gmem_word;
typedef __attribute__((address_space(3))) unsigned lds_word;

__device__ __forceinline__ void gload16(const void* g, void* l) {
    // async global->LDS, 16B per lane; LDS dest = wave-uniform base + lane*16
    __builtin_amdgcn_global_load_lds((gmem_word*)g, (lds_word*)l, 16, 0, 0);
}

// XOR swizzle: involution on byte addresses (bits 4-6 ^= bits 7-9)
__device__ __forceinline__ int swz(int byte) {
    return byte ^ (((byte >> 7) & 7) << 4);
}

// ---------------------------------------------------------------- transpose in
__global__ __launch_bounds__(256) void transpose_in(const float* __restrict__ x,
                                                    float* __restrict__ xl,
                                                    __hip_bfloat16* __restrict__ xlb) {
    __shared__ float tile[32][33];
    int b = blockIdx.z;
    int c0 = blockIdx.y * 32;
    int p0 = blockIdx.x * 32;
    int tx = threadIdx.x, ty = threadIdx.y;   // block (32,8)
#pragma unroll
    for (int q = 0; q < 4; ++q) {
        int c = c0 + ty + q * 8;
        tile[ty + q * 8][tx] = x[((size_t)b * Cc + c) * HW + p0 + tx];
    }
    __syncthreads();
#pragma unroll
    for (int q = 0; q < 4; ++q) {
        int p = p0 + ty + q * 8;
        float v = tile[tx][ty + q * 8];
        size_t idx = ((size_t)b * HW + p) * Cc + c0 + tx;
        xl[idx] = v;
        xlb[idx] = __float2bfloat16(v);
    }
}

// ---------------------------------------------------------------- weight repacks
__global__ __launch_bounds__(256) void repack_qkvt(const float* __restrict__ WQ,
                                                   const float* __restrict__ WK,
                                                   const float* __restrict__ WV,
                                                   __hip_bfloat16* __restrict__ Wt) {
    int t = blockIdx.x * 256 + threadIdx.x;
    if (t >= 3 * Cc * Cc) return;
    int n = t / Cc;
    int c = t % Cc;
    int g = n / Cc;
    int r = n % Cc;
    int h = r / HD, d = r % HD;
    const float* W = (g == 0) ? WQ : ((g == 1) ? WK : WV);
    Wt[t] = __float2bfloat16(W[((size_t)h * Cc + c) * HD + d]);
}

__global__ __launch_bounds__(256) void repack_wot(const float* __restrict__ WO,
                                                  __hip_bfloat16* __restrict__ Wt) {
    int t = blockIdx.x * 256 + threadIdx.x;
    if (t >= Cc * Cc) return;
    int n = t / Cc;
    int c = t % Cc;
    Wt[t] = __float2bfloat16(WO[(size_t)c * Cc + n]);
}

__global__ __launch_bounds__(256) void cast_bf16(const float* __restrict__ in,
                                                 __hip_bfloat16* __restrict__ out, int n) {
    int t = blockIdx.x * 256 + threadIdx.x;
    if (t < n) out[t] = __float2bfloat16(in[t]);
}

// ---------------------------------------------------------------- bf16 MFMA GEMM (128x96)
// C (MxN) = A (MxK bf16 rm) * Bw^T, Bw (NxK bf16 rm) [+bias][relu]
// Tile 128x96, BK=32, 4 waves (2x2), wave tile 64x48. Swizzled LDS.
template <bool OUT_BF16, bool BIAS, bool RELU>
__global__ __launch_bounds__(256) void gemm_mfma(const __hip_bfloat16* __restrict__ A,
                                                 const __hip_bfloat16* __restrict__ Bw,
                                                 const float* __restrict__ bias,
                                                 void* __restrict__ Cout,
                                                 int M, int N, int K) {
    __shared__ __hip_bfloat16 As[2][128 * 32];
    __shared__ __hip_bfloat16 Bs[2][96 * 32];
    const int tid = threadIdx.x;
    const int wave = tid >> 6, lane = tid & 63;
    const int l16 = lane & 15, lq = lane >> 4;
    const int wr = wave >> 1, wc = wave & 1;
    const int bm = blockIdx.y * 128;
    const int bn = blockIdx.x * 96;
    const int nt = K >> 5;
    const char* Ab = (const char*)A;
    const char* Bb = (const char*)Bw;

    f32x4 acc[4][3] = {};

    auto stage = [&](int buf, int t) {
        const size_t k0b = (size_t)(t << 5) * 2;
        for (int c = wave; c < 14; c += 4) {
            if (c < 8) {
                int s = (c << 10) + lane * 16;
                int u = swz(s);
                int row = u >> 6, koff = u & 63;
                gload16(Ab + ((size_t)(bm + row) * K) * 2 + k0b + koff, &As[buf][c << 9]);
            } else {
                int s = ((c - 8) << 10) + lane * 16;
                int u = swz(s);
                int row = u >> 6, koff = u & 63;
                gload16(Bb + ((size_t)(bn + row) * K) * 2 + k0b + koff, &Bs[buf][(c - 8) << 9]);
            }
        }
    };

    int aoff[4], boff[3];
#pragma unroll
    for (int m = 0; m < 4; ++m)
        aoff[m] = swz((wr * 64 + m * 16 + l16) * 64 + lq * 16);
#pragma unroll
    for (int n = 0; n < 3; ++n)
        boff[n] = swz((wc * 48 + n * 16 + l16) * 64 + lq * 16);

    stage(0, 0);
    __syncthreads();
    int cur = 0;
    for (int t = 0; t < nt; ++t) {
        if (t + 1 < nt) stage(cur ^ 1, t + 1);
        const char* Ac = (const char*)&As[cur][0];
        const char* Bc = (const char*)&Bs[cur][0];
        bf16x8 a[4], b[3];
#pragma unroll
        for (int m = 0; m < 4; ++m) a[m] = *(const bf16x8*)(Ac + aoff[m]);
#pragma unroll
        for (int n = 0; n < 3; ++n) b[n] = *(const bf16x8*)(Bc + boff[n]);
#pragma unroll
        for (int m = 0; m < 4; ++m)
#pragma unroll
            for (int n = 0; n < 3; ++n)
                acc[m][n] = __builtin_amdgcn_mfma_f32_16x16x32_bf16(a[m], b[n], acc[m][n], 0, 0, 0);
        __syncthreads();
        cur ^= 1;
    }

#pragma unroll
    for (int m = 0; m < 4; ++m) {
#pragma unroll
        for (int n = 0; n < 3; ++n) {
            const int col = bn + wc * 48 + n * 16 + l16;
            const float bv = BIAS ? bias[col] : 0.f;
#pragma unroll
            for (int r = 0; r < 4; ++r) {
                const int row = bm + wr * 64 + m * 16 + lq * 4 + r;
                float v = acc[m][n][r] + bv;
                if (RELU) v = fmaxf(v, 0.f);
                if (OUT_BF16)
                    ((__hip_bfloat16*)Cout)[(size_t)row * N + col] = __float2bfloat16(v);
                else
                    ((float*)Cout)[(size_t)row * N + col] = v;
            }
        }
    }
}

// ---------------------------------------------------------------- GEMM + fused LayerNorm epilogue
// dst_row = LN(A*Bw^T [+bias]) variants. N fixed = 288 (full row per block).
// Tile 32x288, BK=32, 4 waves (wr x wc = 2x2), wave tile 16x144, acc[9].
// EPI=0: yln = bf16( relu(LN(x; gam,bet)) ), row-major (for W_O -> LN1 -> ReLU)
// EPI=1: out[(b*288+col)*HW+p] = relu(LN(x; gam,bet) + resid[row*288+col])  (FFN2 path)
template <bool BIAS, int EPI>
__global__ __launch_bounds__(256) void gemm_ln(const __hip_bfloat16* __restrict__ A,
                                               const __hip_bfloat16* __restrict__ Bw,
                                               const float* __restrict__ bias,
                                               const float* __restrict__ gam,
                                               const float* __restrict__ bet,
                                               const float* __restrict__ resid,
                                               void* __restrict__ dst,
                                               int K) {
    __shared__ __hip_bfloat16 As[2][32 * 32];    // 2 KB each
    __shared__ __hip_bfloat16 Bs[2][288 * 32];   // 18 KB each
    __shared__ float red[2][2][32];              // [sum|sq][wc][row]
    const int tid = threadIdx.x;
    const int wave = tid >> 6, lane = tid & 63;
    const int l16 = lane & 15, lq = lane >> 4;
    const int wr = wave >> 1, wc = wave & 1;
    const int bm = blockIdx.x * 32;
    const int nt = K >> 5;
    const char* Ab = (const char*)A;
    const char* Bb = (const char*)Bw;
    const size_t Ks2 = (size_t)K * 2;

    f32x4 acc[9] = {};

    auto stage = [&](int buf, int t) {
        const size_t k0b = (size_t)(t << 5) * 2;
        for (int c = wave; c < 20; c += 4) {
            if (c < 2) {
                int s = (c << 10) + lane * 16;
                int u = swz(s);
                int row = u >> 6, koff = u & 63;
                gload16(Ab + (size_t)(bm + row) * Ks2 + k0b + koff, &As[buf][c << 9]);
            } else {
                int s = ((c - 2) << 10) + lane * 16;
                int u = swz(s);
                int row = u >> 6, koff = u & 63;
                gload16(Bb + (size_t)row * Ks2 + k0b + koff, &Bs[buf][(c - 2) << 9]);
            }
        }
    };

    const int aoff = swz((wr * 16 + l16) * 64 + lq * 16);
    int boff[9];
#pragma unroll
    for (int n = 0; n < 9; ++n)
        boff[n] = swz((wc * 144 + n * 16 + l16) * 64 + lq * 16);

    stage(0, 0);
    __syncthreads();
    int cur = 0;
    for (int t = 0; t < nt; ++t) {
        if (t + 1 < nt) stage(cur ^ 1, t + 1);
        const char* Ac = (const char*)&As[cur][0];
        const char* Bc = (const char*)&Bs[cur][0];
        bf16x8 a = *(const bf16x8*)(Ac + aoff);
        bf16x8 b[9];
#pragma unroll
        for (int n = 0; n < 9; ++n) b[n] = *(const bf16x8*)(Bc + boff[n]);
#pragma unroll
        for (int n = 0; n < 9; ++n)
            acc[n] = __builtin_amdgcn_mfma_f32_16x16x32_bf16(a, b[n], acc[n], 0, 0, 0);
        __syncthreads();
        cur ^= 1;
    }

    // ---- epilogue: bias add, then LN over the full 288-wide row
    if (BIAS) {
#pragma unroll
        for (int n = 0; n < 9; ++n) {
            const float bv = bias[wc * 144 + n * 16 + l16];
#pragma unroll
            for (int r = 0; r < 4; ++r) acc[n][r] += bv;
        }
    }
    float sum[4] = {0.f, 0.f, 0.f, 0.f}, sq[4] = {0.f, 0.f, 0.f, 0.f};
#pragma unroll
    for (int n = 0; n < 9; ++n)
#pragma unroll
        for (int r = 0; r < 4; ++r) { sum[r] += acc[n][r]; sq[r] += acc[n][r] * acc[n][r]; }
#pragma unroll
    for (int s = 8; s >= 1; s >>= 1) {
#pragma unroll
        for (int r = 0; r < 4; ++r) { sum[r] += __shfl_xor(sum[r], s); sq[r] += __shfl_xor(sq[r], s); }
    }
    if (l16 == 0) {
#pragma unroll
        for (int r = 0; r < 4; ++r) {
            red[0][wc][wr * 16 + lq * 4 + r] = sum[r];
            red[1][wc][wr * 16 + lq * 4 + r] = sq[r];
        }
    }
    __syncthreads();
    float mean[4], rstd[4];
#pragma unroll
    for (int r = 0; r < 4; ++r) {
        const int rl = wr * 16 + lq * 4 + r;
        const float S = red[0][0][rl] + red[0][1][rl];
        const float Q = red[1][0][rl] + red[1][1][rl];
        mean[r] = S * (1.f / Cc);
        rstd[r] = rsqrtf(Q * (1.f / Cc) - mean[r] * mean[r] + 1e-5f);
    }
#pragma unroll
    for (int n = 0; n < 9; ++n) {
        const int col = wc * 144 + n * 16 + l16;
        const float gm = gam[col], bt = bet[col];
#pragma unroll
        for (int r = 0; r < 4; ++r) {
            const int row = bm + wr * 16 + lq * 4 + r;
            float y = (acc[n][r] - mean[r]) * rstd[r] * gm + bt;
            if (EPI == 0) {
                ((__hip_bfloat16*)dst)[(size_t)row * Cc + col] = __float2bfloat16(fmaxf(y, 0.f));
            } else {
                const float res = resid[(size_t)row * Cc + col];
                const int b = row / HW, p = row % HW;
                ((float*)dst)[((size_t)b * Cc + col) * HW + p] = fmaxf(y + res, 0.f);
            }
        }
    }
}

// ---------------------------------------------------------------- attention
__global__ __launch_bounds__(256) void attn_kernel(const __hip_bfloat16* __restrict__ qkv,
                                                   __hip_bfloat16* __restrict__ aout) {
    int t = blockIdx.x * 256 + threadIdx.x;
    int d = t & 31;
    int ph = t >> 5;
    if (ph >= 16928 * 9) return;
    int h = ph % 9;
    int pix = ph / 9;
    int b = pix / (46 * 46);
    int r = pix % (46 * 46);
    int i = r / 46 + 1;
    int j = r % 46 + 1;
    int m = b * HW + i * Ww + j;
    int hd = h * HD + d;
    float q = __bfloat162float(qkv[(size_t)m * 864 + hd]);
    float logits[9];
    int mns[9];
#pragma unroll
    for (int n = 0; n < 9; ++n) {
        int di = n / 3, dj = n % 3;
        int mn = b * HW + (i - 1 + di) * Ww + (j - 1 + dj);
        mns[n] = mn;
        float kv = __bfloat162float(qkv[(size_t)mn * 864 + 288 + hd]);
        float p = q * kv;
#pragma unroll
        for (int s = 16; s >= 1; s >>= 1) p += __shfl_xor(p, s);
        logits[n] = p * 0.17677669529663687f;
    }
    float mx = logits[0];
#pragma unroll
    for (int n = 1; n < 9; ++n) mx = fmaxf(mx, logits[n]);
    float w[9];
    float sum = 0.f;
#pragma unroll
    for (int n = 0; n < 9; ++n) { w[n] = expf(logits[n] - mx); sum += w[n]; }
    float inv = 1.f / sum;
    float o = 0.f;
#pragma unroll
    for (int n = 0; n < 9; ++n)
        o += w[n] * __bfloat162float(qkv[(size_t)mns[n] * 864 + 576 + hd]);
    aout[(size_t)m * Cc + hd] = __float2bfloat16(o * inv);
}

// ---------------------------------------------------------------- ws-too-small sentinel
__global__ void sentinel_kernel(float* out, float val) {
    out[threadIdx.x] = val;
}

extern "C" void kernel_launch(void* const* d_in, const int* in_sizes, int n_in,
                              void* d_out, int out_size, void* d_ws, size_t ws_size,
                              hipStream_t stream) {
    const float* x   = (const float*)d_in[0];
    const float* WQ  = (const float*)d_in[1];
    const float* WK  = (const float*)d_in[2];
    const float* WV  = (const float*)d_in[3];
    const float* WO  = (const float*)d_in[4];
    const float* f1w = (const float*)d_in[5];
    const float* f1b = (const float*)d_in[6];
    const float* f2w = (const float*)d_in[7];
    const float* f2b = (const float*)d_in[8];
    const float* g1  = (const float*)d_in[9];
    const float* b1  = (const float*)d_in[10];
    const float* g2  = (const float*)d_in[11];
    const float* b2  = (const float*)d_in[12];

    char* ws = (char*)d_ws;
    size_t off = 0;
    auto alloc = [&](size_t bytes) { void* p = ws + off; off += (bytes + 255) & ~(size_t)255; return p; };

    float*          xl    = (float*)alloc((size_t)Mtot * Cc * 4);
    __hip_bfloat16* xlb   = (__hip_bfloat16*)alloc((size_t)Mtot * Cc * 2);   // aliased by aout later
    __hip_bfloat16* wqkvt = (__hip_bfloat16*)alloc((size_t)3 * Cc * Cc * 2);
    char*           big   = (char*)alloc((size_t)Mtot * 3 * Cc * 2);          // qkv bf16
    __hip_bfloat16* wot   = (__hip_bfloat16*)alloc((size_t)Cc * Cc * 2);
    __hip_bfloat16* yln   = (__hip_bfloat16*)alloc((size_t)Mtot * Cc * 2);
    __hip_bfloat16* w1b   = (__hip_bfloat16*)alloc((size_t)Cff * Cc * 2);
    __hip_bfloat16* mid   = (__hip_bfloat16*)alloc((size_t)Mtot * Cff * 2);
    __hip_bfloat16* w2b   = (__hip_bfloat16*)alloc((size_t)Cff * Cc * 2);

    __hip_bfloat16* qkv  = (__hip_bfloat16*)big;   // live: QKV gemm -> attn
    __hip_bfloat16* aout = xlb;                    // live after xlb dead (post QKV gemm)

    if (ws_size < off) {
        sentinel_kernel<<<1, 256, 0, stream>>>((float*)d_out, (float)off * 1e-6f);
        return;
    }

    transpose_in<<<dim3(HW / 32, Cc / 32, Bn), dim3(32, 8), 0, stream>>>(x, xl, xlb);
    repack_qkvt<<<(3 * Cc * Cc + 255) / 256, 256, 0, stream>>>(WQ, WK, WV, wqkvt);
    repack_wot<<<(Cc * Cc + 255) / 256, 256, 0, stream>>>(WO, wot);
    cast_bf16<<<(Cff * Cc + 255) / 256, 256, 0, stream>>>(f1w, w1b, Cff * Cc);
    cast_bf16<<<(Cff * Cc + 255) / 256, 256, 0, stream>>>(f2w, w2b, Cff * Cc);

    // QKV: (M x 288) * (288 x 864) -> bf16
    gemm_mfma<true, false, false><<<dim3(864 / 96, Mtot / 128), 256, 0, stream>>>(
        xlb, wqkvt, nullptr, qkv, Mtot, 3 * Cc, Cc);

    // attention (border rows of aout = 0 implements the zero-pad)
    hipMemsetAsync(aout, 0, (size_t)Mtot * Cc * 2, stream);
    attn_kernel<<<(16928 * 9 * 32) / 256, 256, 0, stream>>>(qkv, aout);

    // W_O + LN1 + ReLU fused: yln = bf16(relu(LN(aout * WO)))
    gemm_ln<false, 0><<<Mtot / 32, 256, 0, stream>>>(
        aout, wot, nullptr, g1, b1, nullptr, yln, Cc);

    // FFN1: (M x 288) * (288 x 2592) + bias, relu -> bf16
    gemm_mfma<true, true, true><<<dim3(Cff / 96, Mtot / 128), 256, 0, stream>>>(
        yln, w1b, f1b, mid, Mtot, Cff, Cc);

    // FFN2 + LN2 + residual + ReLU + transpose-out fused
    gemm_ln<true, 1><<<Mtot / 32, 256, 0, stream>>>(
        mid, w2b, f2b, g2, b2, xl, (float*)d_out, Cff);
}